// Round 8
// baseline (37.484 us; speedup 1.0000x reference)
//
#include <hip/hip_runtime.h>
#include <math.h>

// Problem constants: inputs (128, 64, 64, 32) fp32
#define BB 128
#define NN 64
#define DD 2048            // 64*32
#define NBLK 512           // 4 quarter-blocks per batch
#define NTHR 512           // 8 waves

__device__ __forceinline__ float wave_reduce_sum(float v) {
    #pragma unroll
    for (int off = 32; off > 0; off >>= 1)
        v += __shfl_down(v, off, 64);
    return v;
}

__device__ __forceinline__ unsigned long long pack2(float a, float b) {
    return ((unsigned long long)__float_as_uint(b) << 32) |
            (unsigned long long)__float_as_uint(a);
}
__device__ __forceinline__ float2 unpack2(unsigned long long v) {
    return make_float2(__uint_as_float((unsigned)v),
                       __uint_as_float((unsigned)(v >> 32)));
}

// Block u -> batch b=u&127, quarter q=u>>7 (rows 16q..16q+15).
// Fence-free: cross-block data moves ONLY via relaxed agent-scope atomics
// (both store and load sides -> coherence point; R7-proven). Per-wave
// s_waitcnt vmcnt(0) + __syncthreads before counter bumps. No spins:
// last-arrival blocks do the combines (deterministic fixed-order sums).
__global__ __launch_bounds__(NTHR) void fused_loss_kernel(
        const float* __restrict__ x,
        unsigned long long* __restrict__ vq8,   // [512][1024] packed float2
        double* __restrict__ diag_part,         // [512]
        double* __restrict__ partials,          // [128]
        unsigned* __restrict__ bcnt,            // [128] pre-zeroed
        unsigned* __restrict__ gcnt,            // [1]   pre-zeroed
        float* __restrict__ out) {
    const unsigned u = blockIdx.x;
    const int b = (int)(u & 127u);
    const int q = (int)(u >> 7);
    const int t = threadIdx.x;
    const int lane = t & 63, wid = t >> 6;   // 8 waves

    __shared__ float invs[16];
    __shared__ float diag_w[8];
    __shared__ float red[8];
    __shared__ int flag;
    __shared__ double sd[BB];

    const float* xq = x + ((size_t)b * NN + q * 16) * DD;

    // ---- Phase A: own 16 rows, wave w -> rows 2w, 2w+1 (float4 stream) ----
    float diag = 0.f;
    #pragma unroll
    for (int rr = 0; rr < 2; ++rr) {
        const int row = wid * 2 + rr;
        const float4* p = reinterpret_cast<const float4*>(xq + (size_t)row * DD);
        float s = 0.f;
        #pragma unroll
        for (int j = 0; j < 8; ++j) {          // 512 float4 per row
            float4 a = p[lane + 64 * j];
            s += a.x * a.x + a.y * a.y + a.z * a.z + a.w * a.w;
        }
        s = wave_reduce_sum(s);
        if (lane == 0) {
            float r = fmaxf(sqrtf(s), 1e-12f);
            float inv = 1.0f / r;
            invs[row] = inv;
            diag += s * inv * inv;             // ||att_row||^2
        }
    }
    if (lane == 0) diag_w[wid] = diag;
    __syncthreads();

    // ---- Phase B: thread t -> cols 4t..4t+3 over own 16 rows (L2-hot) ----
    {
        const float4* x4 = reinterpret_cast<const float4*>(xq);
        float4 v = make_float4(0.f, 0.f, 0.f, 0.f);
        #pragma unroll
        for (int n = 0; n < 16; ++n) {
            float4 a = x4[(size_t)n * (DD / 4) + t];
            const float iv = invs[n];
            v.x = fmaf(a.x, iv, v.x);
            v.y = fmaf(a.y, iv, v.y);
            v.z = fmaf(a.z, iv, v.z);
            v.w = fmaf(a.w, iv, v.w);
        }
        // publish quarter-vector at the coherence point (atomic stores)
        unsigned long long* dst = vq8 + (size_t)u * (DD / 2) + 2 * t;
        __hip_atomic_store(dst + 0, pack2(v.x, v.y),
                           __ATOMIC_RELAXED, __HIP_MEMORY_SCOPE_AGENT);
        __hip_atomic_store(dst + 1, pack2(v.z, v.w),
                           __ATOMIC_RELAXED, __HIP_MEMORY_SCOPE_AGENT);
    }
    // every wave drains its own stores, then block-wide rendezvous
    asm volatile("s_waitcnt vmcnt(0)" ::: "memory");
    __syncthreads();

    if (t == 0) {
        double dsum = 0.0;
        #pragma unroll
        for (int w = 0; w < 8; ++w) dsum += (double)diag_w[w];
        __hip_atomic_store(&diag_part[u], dsum,
                           __ATOMIC_RELAXED, __HIP_MEMORY_SCOPE_AGENT);
        asm volatile("s_waitcnt vmcnt(0)" ::: "memory");
        unsigned old = __hip_atomic_fetch_add(&bcnt[b], 1u,
                        __ATOMIC_RELAXED, __HIP_MEMORY_SCOPE_AGENT);
        flag = (old == 3u) ? 1 : 0;
    }
    __syncthreads();
    if (!flag) return;

    // ---- Batch finisher (4th arrival): v_b = sum of 4 quarters ----
    {
        float vx = 0.f, vy = 0.f, vz = 0.f, vw = 0.f;
        #pragma unroll
        for (int qq = 0; qq < 4; ++qq) {
            const unsigned long long* src =
                vq8 + (size_t)(b + 128 * qq) * (DD / 2) + 2 * t;
            float2 lo = unpack2(__hip_atomic_load(src + 0,
                            __ATOMIC_RELAXED, __HIP_MEMORY_SCOPE_AGENT));
            float2 hi = unpack2(__hip_atomic_load(src + 1,
                            __ATOMIC_RELAXED, __HIP_MEMORY_SCOPE_AGENT));
            vx += lo.x; vy += lo.y; vz += hi.x; vw += hi.y;
        }
        float p = vx * vx + vy * vy + vz * vz + vw * vw;
        p = wave_reduce_sum(p);
        if (lane == 0) red[wid] = p;
    }
    __syncthreads();
    if (t == 0) {
        double sp = 0.0, dp = 0.0;
        #pragma unroll
        for (int w = 0; w < 8; ++w) sp += (double)red[w];
        #pragma unroll
        for (int qq = 0; qq < 4; ++qq)
            dp += __hip_atomic_load(&diag_part[b + 128 * qq],
                        __ATOMIC_RELAXED, __HIP_MEMORY_SCOPE_AGENT);
        __hip_atomic_store(&partials[b], sp - dp,
                        __ATOMIC_RELAXED, __HIP_MEMORY_SCOPE_AGENT);
        asm volatile("s_waitcnt vmcnt(0)" ::: "memory");
        unsigned old = __hip_atomic_fetch_add(gcnt, 1u,
                        __ATOMIC_RELAXED, __HIP_MEMORY_SCOPE_AGENT);
        flag = (old == (unsigned)(BB - 1)) ? 1 : 0;
    }
    __syncthreads();
    if (!flag) return;

    // ---- Global finisher: fixed-order tree over 128 batch partials ----
    if (t < BB)
        sd[t] = __hip_atomic_load(&partials[t],
                        __ATOMIC_RELAXED, __HIP_MEMORY_SCOPE_AGENT);
    __syncthreads();
    #pragma unroll
    for (int off = BB / 2; off > 0; off >>= 1) {
        if (t < off) sd[t] += sd[t + off];
        __syncthreads();
    }
    if (t == 0) out[0] = (float)(sd[0] / (double)BB);
}

extern "C" void kernel_launch(void* const* d_in, const int* in_sizes, int n_in,
                              void* d_out, int out_size, void* d_ws, size_t ws_size,
                              hipStream_t stream) {
    const float* x = (const float*)d_in[0];
    float* out = (float*)d_out;
    char* ws = (char*)d_ws;

    unsigned long long* vq8 = (unsigned long long*)ws;     // 4 MB [0, 4194304)
    double* diag_part = (double*)(ws + 4194304);           // 4 KB
    double* partials  = (double*)(ws + 4198400);           // 1 KB
    unsigned* bcnt    = (unsigned*)(ws + 4199424);         // 512 B
    unsigned* gcnt    = (unsigned*)(ws + 4199936);         // 4 B

    hipMemsetAsync(ws + 4199424, 0, 516, stream);          // zero both counters
    fused_loss_kernel<<<NBLK, NTHR, 0, stream>>>(x, vq8, diag_part, partials,
                                                 bcnt, gcnt, out);
}

// Round 9
// 30.068 us; speedup vs baseline: 1.2467x; 1.2467x over previous
//
#include <hip/hip_runtime.h>
#include <math.h>

// Problem constants: inputs (128, 64, 64, 32) fp32
#define BB 128
#define NN 64
#define DD 2048            // 64*32
#define NBLK1 256          // K1: block u -> batch u>>1, row-half u&1 (32 rows)
#define NTHR1 1024         // 16 waves
#define GROUP 8            // rows per streaming group (64 KB, L2-resident)

__device__ __forceinline__ float wave_reduce_sum(float v) {
    #pragma unroll
    for (int off = 32; off > 0; off >>= 1)
        v += __shfl_down(v, off, 64);
    return v;
}

// K1: no cross-block communication at all. Grouped stream: sumsq 8 rows
// (HBM), compute inv, immediately re-read the hot 64 KB to accumulate the
// column vector. Kernel boundary = the only sync we need.
__global__ __launch_bounds__(NTHR1) void half_batch_kernel(
        const float* __restrict__ x,
        float* __restrict__ vhalf,       // [256][2048]
        double* __restrict__ diag_half) { // [256]
    const int u = blockIdx.x;
    const int b = u >> 1, h = u & 1;
    const int t = threadIdx.x;
    const int lane = t & 63, wid = t >> 6;   // 16 waves

    __shared__ float swave[16];
    __shared__ float invs[GROUP];
    __shared__ float diag_t[GROUP];

    const float* xb = x + ((size_t)b * NN + h * 32) * DD;   // own 32 rows
    const float2* x2 = reinterpret_cast<const float2*>(xb);

    float2 v = make_float2(0.f, 0.f);    // cols 2t, 2t+1 accumulator
    float diag_acc = 0.f;                // live in t<8 threads

    #pragma unroll
    for (int g = 0; g < 32 / GROUP; ++g) {
        // -- A: wave w sums row g*8 + (w>>1), col-half (w&1) --
        {
            const int row = g * GROUP + (wid >> 1);
            const float4* p = reinterpret_cast<const float4*>(
                xb + (size_t)row * DD + (wid & 1) * 1024);
            float s = 0.f;
            #pragma unroll
            for (int j = 0; j < 4; ++j) {          // 256 float4 per half-row
                float4 a = p[lane + 64 * j];
                s += a.x * a.x + a.y * a.y + a.z * a.z + a.w * a.w;
            }
            s = wave_reduce_sum(s);
            if (lane == 0) swave[wid] = s;
        }
        __syncthreads();
        if (t < GROUP) {
            const float ss = swave[2 * t] + swave[2 * t + 1];
            const float r = fmaxf(sqrtf(ss), 1e-12f);
            const float inv = 1.0f / r;
            invs[t] = inv;
            diag_acc += ss * inv * inv;            // ||att_row||^2
        }
        __syncthreads();
        // -- B: just-streamed 64 KB is L2-hot; accumulate column vector --
        #pragma unroll
        for (int n = 0; n < GROUP; ++n) {
            const float2 a = x2[(size_t)(g * GROUP + n) * (DD / 2) + t];
            const float iv = invs[n];
            v.x = fmaf(a.x, iv, v.x);
            v.y = fmaf(a.y, iv, v.y);
        }
        __syncthreads();                           // invs reused next group
    }

    reinterpret_cast<float2*>(vhalf + (size_t)u * DD)[t] = v;
    if (t < GROUP) diag_t[t] = diag_acc;
    __syncthreads();
    if (t == 0) {
        double d = 0.0;
        #pragma unroll
        for (int i = 0; i < GROUP; ++i) d += (double)diag_t[i];
        diag_half[u] = d;
    }
}

// K2: combine halves, per-batch partial, fence-free last-block global tree.
__global__ __launch_bounds__(256) void combine_kernel(
        const float* __restrict__ vhalf,
        const double* __restrict__ diag_half,
        double* __restrict__ partials,   // [128]
        unsigned* __restrict__ counter,  // pre-zeroed
        float* __restrict__ out) {
    const int b = blockIdx.x;
    const int t = threadIdx.x;
    const int lane = t & 63, wid = t >> 6;   // 4 waves

    __shared__ float red[4];
    __shared__ int flag;
    __shared__ double sd[BB];

    // thread t -> cols 8t..8t+7
    const float4* f4 = reinterpret_cast<const float4*>(vhalf);
    float4 a0 = f4[(size_t)(2 * b) * (DD / 4) + 2 * t];
    float4 a1 = f4[(size_t)(2 * b) * (DD / 4) + 2 * t + 1];
    float4 b0 = f4[(size_t)(2 * b + 1) * (DD / 4) + 2 * t];
    float4 b1 = f4[(size_t)(2 * b + 1) * (DD / 4) + 2 * t + 1];
    const float cx = a0.x + b0.x, cy = a0.y + b0.y, cz = a0.z + b0.z, cw = a0.w + b0.w;
    const float dx = a1.x + b1.x, dy = a1.y + b1.y, dz = a1.z + b1.z, dw = a1.w + b1.w;
    float p = cx * cx + cy * cy + cz * cz + cw * cw
            + dx * dx + dy * dy + dz * dz + dw * dw;
    p = wave_reduce_sum(p);
    if (lane == 0) red[wid] = p;
    __syncthreads();

    if (t == 0) {
        double sp = (double)red[0] + (double)red[1]
                  + (double)red[2] + (double)red[3];
        double dp = diag_half[2 * b] + diag_half[2 * b + 1];
        __hip_atomic_store(&partials[b], sp - dp,
                           __ATOMIC_RELAXED, __HIP_MEMORY_SCOPE_AGENT);
        asm volatile("s_waitcnt vmcnt(0)" ::: "memory");   // drain my store
        unsigned old = __hip_atomic_fetch_add(counter, 1u,
                        __ATOMIC_RELAXED, __HIP_MEMORY_SCOPE_AGENT);
        flag = (old == (unsigned)(BB - 1)) ? 1 : 0;
    }
    __syncthreads();
    if (!flag) return;

    // last block: deterministic fixed-order tree over 128 partials
    if (t < BB)
        sd[t] = __hip_atomic_load(&partials[t],
                        __ATOMIC_RELAXED, __HIP_MEMORY_SCOPE_AGENT);
    __syncthreads();
    #pragma unroll
    for (int off = BB / 2; off > 0; off >>= 1) {
        if (t < off) sd[t] += sd[t + off];
        __syncthreads();
    }
    if (t == 0) out[0] = (float)(sd[0] / (double)BB);
}

extern "C" void kernel_launch(void* const* d_in, const int* in_sizes, int n_in,
                              void* d_out, int out_size, void* d_ws, size_t ws_size,
                              hipStream_t stream) {
    const float* x = (const float*)d_in[0];
    float* out = (float*)d_out;
    char* ws = (char*)d_ws;

    float* vhalf      = (float*)ws;                 // 256*2048*4 = 2 MB
    double* diag_half = (double*)(ws + 2097152);    // 2 KB
    double* partials  = (double*)(ws + 2099200);    // 1 KB
    unsigned* counter = (unsigned*)(ws + 2100224);  // 4 B

    hipMemsetAsync(counter, 0, 4, stream);
    half_batch_kernel<<<NBLK1, NTHR1, 0, stream>>>(x, vhalf, diag_half);
    combine_kernel<<<BB, 256, 0, stream>>>(vhalf, diag_half, partials,
                                           counter, out);
}

// Round 10
// 28.651 us; speedup vs baseline: 1.3083x; 1.0495x over previous
//
#include <hip/hip_runtime.h>
#include <math.h>

// Problem constants: inputs (128, 64, 64, 32) fp32
#define BB 128
#define NN 64
#define DD 2048            // 64*32
#define ROWS (BB * NN)     // 8192

__device__ __forceinline__ float wave_reduce_sum_down(float v) {
    #pragma unroll
    for (int off = 32; off > 0; off >>= 1)
        v += __shfl_down(v, off, 64);
    return v;
}

// K1: fill-kernel shape (256 thr, many blocks). Each wave owns RPW rows,
// fully in registers: sumsq via xor-butterfly (all lanes get sum -> no
// barrier), inv lane-uniform, FMA into column accumulators. One LDS combine
// at the end. Single HBM pass, no re-read, no main-loop barriers.
template<int RPW>
__global__ __launch_bounds__(256) void stream_kernel(
        const float* __restrict__ x,
        float* __restrict__ vseg,        // [ROWS/RPB][2048]
        float* __restrict__ diag_seg) {  // [ROWS/RPB]
    constexpr int RPB = 4 * RPW;         // rows per block (4 waves)
    constexpr int SEG = NN / RPB;        // segments per batch
    const int u = blockIdx.x;
    const int b = u / SEG, s = u % SEG;
    const int t = threadIdx.x;
    const int lane = t & 63, w = t >> 6; // 4 waves

    const float* xw = x + ((size_t)b * NN + s * RPB + w * RPW) * DD;

    float4 acc[8];
    #pragma unroll
    for (int j = 0; j < 8; ++j) acc[j] = make_float4(0.f, 0.f, 0.f, 0.f);
    float diag = 0.f;                    // lane-uniform

    #pragma unroll
    for (int r = 0; r < RPW; ++r) {
        const float4* p = reinterpret_cast<const float4*>(xw + (size_t)r * DD);
        float4 a[8];
        #pragma unroll
        for (int j = 0; j < 8; ++j) a[j] = p[lane + 64 * j];
        float ss = 0.f;
        #pragma unroll
        for (int j = 0; j < 8; ++j)
            ss += a[j].x * a[j].x + a[j].y * a[j].y
                + a[j].z * a[j].z + a[j].w * a[j].w;
        #pragma unroll
        for (int off = 1; off < 64; off <<= 1)   // butterfly: all lanes get sum
            ss += __shfl_xor(ss, off, 64);
        const float inv = 1.0f / fmaxf(sqrtf(ss), 1e-12f);
        diag += ss * inv * inv;                  // ||att_row||^2
        #pragma unroll
        for (int j = 0; j < 8; ++j) {
            acc[j].x = fmaf(a[j].x, inv, acc[j].x);
            acc[j].y = fmaf(a[j].y, inv, acc[j].y);
            acc[j].z = fmaf(a[j].z, inv, acc[j].z);
            acc[j].w = fmaf(a[j].w, inv, acc[j].w);
        }
    }

    // cross-wave combine: [4][2048] floats = 32 KB LDS, conflict-free layout
    __shared__ float lds[4][DD];
    __shared__ float dl[4];
    float4* lw = reinterpret_cast<float4*>(lds[w]);
    #pragma unroll
    for (int j = 0; j < 8; ++j) lw[lane + 64 * j] = acc[j];
    if (lane == 0) dl[w] = diag;
    __syncthreads();

    // thread t -> float4 indices t, t+256 (byte 16t: bank-conflict-free)
    float4 o0 = make_float4(0.f, 0.f, 0.f, 0.f);
    float4 o1 = make_float4(0.f, 0.f, 0.f, 0.f);
    #pragma unroll
    for (int ww = 0; ww < 4; ++ww) {
        const float4* lr = reinterpret_cast<const float4*>(lds[ww]);
        float4 p0 = lr[t], p1 = lr[t + 256];
        o0.x += p0.x; o0.y += p0.y; o0.z += p0.z; o0.w += p0.w;
        o1.x += p1.x; o1.y += p1.y; o1.z += p1.z; o1.w += p1.w;
    }
    float4* dst = reinterpret_cast<float4*>(vseg + (size_t)u * DD);
    dst[t] = o0;
    dst[t + 256] = o1;
    if (t == 0) diag_seg[u] = dl[0] + dl[1] + dl[2] + dl[3];
}

// K2: per-batch combine of SEG segment vectors + fence-free last-block tree.
template<int SEG>
__global__ __launch_bounds__(256) void combine_kernel(
        const float* __restrict__ vseg,
        const float* __restrict__ diag_seg,
        double* __restrict__ partials,   // [128]
        unsigned* __restrict__ counter,  // pre-zeroed
        float* __restrict__ out) {
    const int b = blockIdx.x;
    const int t = threadIdx.x;
    const int lane = t & 63, wid = t >> 6;   // 4 waves

    __shared__ float red[4];
    __shared__ int flag;
    __shared__ double sd[BB];

    float4 c0 = make_float4(0.f, 0.f, 0.f, 0.f);
    float4 c1 = make_float4(0.f, 0.f, 0.f, 0.f);
    #pragma unroll
    for (int o = 0; o < SEG; ++o) {
        const float4* src = reinterpret_cast<const float4*>(
            vseg + (size_t)(b * SEG + o) * DD);
        float4 a0 = src[t], a1 = src[t + 256];
        c0.x += a0.x; c0.y += a0.y; c0.z += a0.z; c0.w += a0.w;
        c1.x += a1.x; c1.y += a1.y; c1.z += a1.z; c1.w += a1.w;
    }
    float p = c0.x * c0.x + c0.y * c0.y + c0.z * c0.z + c0.w * c0.w
            + c1.x * c1.x + c1.y * c1.y + c1.z * c1.z + c1.w * c1.w;
    p = wave_reduce_sum_down(p);
    if (lane == 0) red[wid] = p;
    __syncthreads();

    if (t == 0) {
        double sp = (double)red[0] + (double)red[1]
                  + (double)red[2] + (double)red[3];
        double dp = 0.0;
        #pragma unroll
        for (int o = 0; o < SEG; ++o) dp += (double)diag_seg[b * SEG + o];
        __hip_atomic_store(&partials[b], sp - dp,
                           __ATOMIC_RELAXED, __HIP_MEMORY_SCOPE_AGENT);
        asm volatile("s_waitcnt vmcnt(0)" ::: "memory");   // drain my store
        unsigned old = __hip_atomic_fetch_add(counter, 1u,
                        __ATOMIC_RELAXED, __HIP_MEMORY_SCOPE_AGENT);
        flag = (old == (unsigned)(BB - 1)) ? 1 : 0;
    }
    __syncthreads();
    if (!flag) return;

    if (t < BB)
        sd[t] = __hip_atomic_load(&partials[t],
                        __ATOMIC_RELAXED, __HIP_MEMORY_SCOPE_AGENT);
    __syncthreads();
    #pragma unroll
    for (int off = BB / 2; off > 0; off >>= 1) {
        if (t < off) sd[t] += sd[t + off];
        __syncthreads();
    }
    if (t == 0) out[0] = (float)(sd[0] / (double)BB);
}

extern "C" void kernel_launch(void* const* d_in, const int* in_sizes, int n_in,
                              void* d_out, int out_size, void* d_ws, size_t ws_size,
                              hipStream_t stream) {
    const float* x = (const float*)d_in[0];
    float* out = (float*)d_out;
    char* ws = (char*)d_ws;

    // Preferred: 8 rows/block -> 1024 segments, ws = 8 MB + tails
    const size_t need8 = (size_t)1024 * DD * 4 + 4096 + 1024 + 4;
    if (ws_size >= need8) {
        float* vseg       = (float*)ws;                      // 8 MB
        float* diag_seg   = (float*)(ws + (size_t)1024 * DD * 4);
        double* partials  = (double*)(ws + (size_t)1024 * DD * 4 + 4096);
        unsigned* counter = (unsigned*)(ws + (size_t)1024 * DD * 4 + 4096 + 1024);
        hipMemsetAsync(counter, 0, 4, stream);
        stream_kernel<2><<<1024, 256, 0, stream>>>(x, vseg, diag_seg);
        combine_kernel<8><<<BB, 256, 0, stream>>>(vseg, diag_seg, partials,
                                                  counter, out);
    } else {
        // Fallback: 16 rows/block -> 512 segments, ws = 4 MB + tails
        float* vseg       = (float*)ws;                      // 4 MB
        float* diag_seg   = (float*)(ws + (size_t)512 * DD * 4);
        double* partials  = (double*)(ws + (size_t)512 * DD * 4 + 2048);
        unsigned* counter = (unsigned*)(ws + (size_t)512 * DD * 4 + 2048 + 1024);
        hipMemsetAsync(counter, 0, 4, stream);
        stream_kernel<4><<<512, 256, 0, stream>>>(x, vseg, diag_seg);
        combine_kernel<4><<<BB, 256, 0, stream>>>(vseg, diag_seg, partials,
                                                  counter, out);
    }
}

// Round 11
// 21.805 us; speedup vs baseline: 1.7191x; 1.3140x over previous
//
#include <hip/hip_runtime.h>
#include <math.h>

// Problem constants: inputs (128, 64, 64, 32) fp32
#define BB 128
#define NN 64
#define DD 2048            // 64*32
#define ROWS (BB * NN)     // 8192

__device__ __forceinline__ float wave_reduce_sum_down(float v) {
    #pragma unroll
    for (int off = 32; off > 0; off >>= 1)
        v += __shfl_down(v, off, 64);
    return v;
}

// K1: 256-thr blocks; each wave owns RPW rows fully in registers. Sumsq via
// xor-butterfly (lane-uniform, no LDS/barrier in main loop), inv, FMA into
// column accumulators. One LDS combine at the end. Block 0 also zeroes the
// K2 counter (kernel boundary = visibility fence).
template<int RPW>
__global__ __launch_bounds__(256) void stream_kernel(
        const float* __restrict__ x,
        float* __restrict__ vseg,        // [ROWS/RPB][2048]
        float* __restrict__ diag_seg,    // [ROWS/RPB]
        unsigned* __restrict__ counter) {
    constexpr int RPB = 4 * RPW;         // rows per block (4 waves)
    constexpr int SEG = NN / RPB;        // segments per batch
    const int u = blockIdx.x;
    const int b = u / SEG, s = u % SEG;
    const int t = threadIdx.x;
    const int lane = t & 63, w = t >> 6; // 4 waves

    if (u == 0 && t == 0) *counter = 0;  // visible to K2 at kernel boundary

    const float* xw = x + ((size_t)b * NN + s * RPB + w * RPW) * DD;

    float4 acc[8];
    #pragma unroll
    for (int j = 0; j < 8; ++j) acc[j] = make_float4(0.f, 0.f, 0.f, 0.f);
    float diag = 0.f;                    // lane-uniform

    #pragma unroll
    for (int r = 0; r < RPW; ++r) {
        const float4* p = reinterpret_cast<const float4*>(xw + (size_t)r * DD);
        float4 a[8];
        #pragma unroll
        for (int j = 0; j < 8; ++j) a[j] = p[lane + 64 * j];
        float ss = 0.f;
        #pragma unroll
        for (int j = 0; j < 8; ++j)
            ss += a[j].x * a[j].x + a[j].y * a[j].y
                + a[j].z * a[j].z + a[j].w * a[j].w;
        #pragma unroll
        for (int off = 1; off < 64; off <<= 1)   // butterfly: all lanes get sum
            ss += __shfl_xor(ss, off, 64);
        const float inv = 1.0f / fmaxf(sqrtf(ss), 1e-12f);
        diag += ss * inv * inv;                  // ||att_row||^2
        #pragma unroll
        for (int j = 0; j < 8; ++j) {
            acc[j].x = fmaf(a[j].x, inv, acc[j].x);
            acc[j].y = fmaf(a[j].y, inv, acc[j].y);
            acc[j].z = fmaf(a[j].z, inv, acc[j].z);
            acc[j].w = fmaf(a[j].w, inv, acc[j].w);
        }
    }

    // cross-wave combine: [4][2048] floats = 32 KB LDS
    __shared__ float lds[4][DD];
    __shared__ float dl[4];
    float4* lw = reinterpret_cast<float4*>(lds[w]);
    #pragma unroll
    for (int j = 0; j < 8; ++j) lw[lane + 64 * j] = acc[j];
    if (lane == 0) dl[w] = diag;
    __syncthreads();

    // thread t -> float4 indices t, t+256 (16B stride: conflict-free)
    float4 o0 = make_float4(0.f, 0.f, 0.f, 0.f);
    float4 o1 = make_float4(0.f, 0.f, 0.f, 0.f);
    #pragma unroll
    for (int ww = 0; ww < 4; ++ww) {
        const float4* lr = reinterpret_cast<const float4*>(lds[ww]);
        float4 p0 = lr[t], p1 = lr[t + 256];
        o0.x += p0.x; o0.y += p0.y; o0.z += p0.z; o0.w += p0.w;
        o1.x += p1.x; o1.y += p1.y; o1.z += p1.z; o1.w += p1.w;
    }
    float4* dst = reinterpret_cast<float4*>(vseg + (size_t)u * DD);
    dst[t] = o0;
    dst[t + 256] = o1;
    if (t == 0) diag_seg[u] = dl[0] + dl[1] + dl[2] + dl[3];
}

// K2: per-batch combine of SEG segment vectors + fence-free last-block tree.
template<int SEG>
__global__ __launch_bounds__(256) void combine_kernel(
        const float* __restrict__ vseg,
        const float* __restrict__ diag_seg,
        double* __restrict__ partials,   // [128]
        unsigned* __restrict__ counter,  // zeroed by K1
        float* __restrict__ out) {
    const int b = blockIdx.x;
    const int t = threadIdx.x;
    const int lane = t & 63, wid = t >> 6;   // 4 waves

    __shared__ float red[4];
    __shared__ int flag;
    __shared__ double sd[BB];

    float4 c0 = make_float4(0.f, 0.f, 0.f, 0.f);
    float4 c1 = make_float4(0.f, 0.f, 0.f, 0.f);
    #pragma unroll
    for (int o = 0; o < SEG; ++o) {
        const float4* src = reinterpret_cast<const float4*>(
            vseg + (size_t)(b * SEG + o) * DD);
        float4 a0 = src[t], a1 = src[t + 256];
        c0.x += a0.x; c0.y += a0.y; c0.z += a0.z; c0.w += a0.w;
        c1.x += a1.x; c1.y += a1.y; c1.z += a1.z; c1.w += a1.w;
    }
    float p = c0.x * c0.x + c0.y * c0.y + c0.z * c0.z + c0.w * c0.w
            + c1.x * c1.x + c1.y * c1.y + c1.z * c1.z + c1.w * c1.w;
    p = wave_reduce_sum_down(p);
    if (lane == 0) red[wid] = p;
    __syncthreads();

    if (t == 0) {
        double sp = (double)red[0] + (double)red[1]
                  + (double)red[2] + (double)red[3];
        double dp = 0.0;
        #pragma unroll
        for (int o = 0; o < SEG; ++o) dp += (double)diag_seg[b * SEG + o];
        __hip_atomic_store(&partials[b], sp - dp,
                           __ATOMIC_RELAXED, __HIP_MEMORY_SCOPE_AGENT);
        asm volatile("s_waitcnt vmcnt(0)" ::: "memory");   // drain my store
        unsigned old = __hip_atomic_fetch_add(counter, 1u,
                        __ATOMIC_RELAXED, __HIP_MEMORY_SCOPE_AGENT);
        flag = (old == (unsigned)(BB - 1)) ? 1 : 0;
    }
    __syncthreads();
    if (!flag) return;

    if (t < BB)
        sd[t] = __hip_atomic_load(&partials[t],
                        __ATOMIC_RELAXED, __HIP_MEMORY_SCOPE_AGENT);
    __syncthreads();
    #pragma unroll
    for (int off = BB / 2; off > 0; off >>= 1) {
        if (t < off) sd[t] += sd[t + off];
        __syncthreads();
    }
    if (t == 0) out[0] = (float)(sd[0] / (double)BB);
}

extern "C" void kernel_launch(void* const* d_in, const int* in_sizes, int n_in,
                              void* d_out, int out_size, void* d_ws, size_t ws_size,
                              hipStream_t stream) {
    const float* x = (const float*)d_in[0];
    float* out = (float*)d_out;
    char* ws = (char*)d_ws;

    // Preferred: RPW=4 -> 512 blocks, vseg 4 MB
    const size_t vbytes = (size_t)512 * DD * 4;
    const size_t need = vbytes + 2048 + 1024 + 4;
    if (ws_size >= need) {
        float* vseg       = (float*)ws;                    // 4 MB
        float* diag_seg   = (float*)(ws + vbytes);         // 2 KB
        double* partials  = (double*)(ws + vbytes + 2048); // 1 KB
        unsigned* counter = (unsigned*)(ws + vbytes + 2048 + 1024);
        stream_kernel<4><<<512, 256, 0, stream>>>(x, vseg, diag_seg, counter);
        combine_kernel<4><<<BB, 256, 0, stream>>>(vseg, diag_seg, partials,
                                                  counter, out);
    } else {
        // Fallback: RPW=8 -> 256 blocks, vseg 2 MB
        const size_t vb2 = (size_t)256 * DD * 4;
        float* vseg       = (float*)ws;                    // 2 MB
        float* diag_seg   = (float*)(ws + vb2);            // 1 KB
        double* partials  = (double*)(ws + vb2 + 1024);    // 1 KB
        unsigned* counter = (unsigned*)(ws + vb2 + 2048);
        stream_kernel<8><<<256, 256, 0, stream>>>(x, vseg, diag_seg, counter);
        combine_kernel<2><<<BB, 256, 0, stream>>>(vseg, diag_seg, partials,
                                                  counter, out);
    }
}